// Round 5
// baseline (156.424 us; speedup 1.0000x reference)
//
#include <hip/hip_runtime.h>

using u8  = unsigned char;
using u16 = unsigned short;
using u32 = unsigned int;
typedef __attribute__((ext_vector_type(8))) short short8;   // 8 bf16 (MFMA A/B frag)
typedef __attribute__((ext_vector_type(4))) float f32x4;    // MFMA C/D frag

#define QMIN 64    // emit screen: v >= 1.984375  (== (int)(v*32+0.5) >= 64)
#define SCAP 96    // per-row spill capacity (expected ~2/row @ 2-slot/16col cells; hot row ~60)
#define CMAX 608   // per-row candidate max (m_all <= ~500 at +7sd)
#define RCAP 96    // ambiguous-band capacity (expected ~20, +10sd)
#define BERR 0.045f   // |v_true - v_list| bound (R10 proof implies <=0.031+2e-5)

__device__ __forceinline__ float bf2f(u16 u) {
    union { u32 i; float f; } c; c.i = ((u32)u) << 16; return c.f;
}
__device__ __forceinline__ u16 f2bf(float f) {
    union { float f; u32 i; } c; c.f = f;
    u32 u = c.i + 0x7FFFu + ((c.i >> 16) & 1u);   // RNE; inputs are finite
    return (u16)(u >> 16);
}

// entry: (n << 19) | fixed19, fixed19 = floor(v*65536) (sat 0x7FFFF) >= 130048
// for valid v >= 1.984 -> 0 is a safe empty sentinel. Saturated -> refine.

// ---------------------------------------------------------------------------
// Kernel 0: FRAGMENT-SWIZZLED bf16 operands + bf16 W_dec + zero cnt + zero seg.
// Swizzle: tile t=(mt*8+kt); lane l holds 8 bf16 at (row=16*mt+(l&15),
// k=32*kt+(l>>4)*8+j) at offset (t*64+l)*8.  (unchanged)
// ---------------------------------------------------------------------------
__global__ __launch_bounds__(256) void prep_convert(const float* __restrict__ x,
                                                    const float* __restrict__ b_dec,
                                                    const float* __restrict__ W_enc,
                                                    const float* __restrict__ W_dec,
                                                    u16* __restrict__ Ap,
                                                    u16* __restrict__ Wb,
                                                    u16* __restrict__ Wd,
                                                    u32* __restrict__ cnt,
                                                    u32* __restrict__ seg) {
    int i = blockIdx.x * 256 + threadIdx.x;     // grid = 6672 blocks exactly
    if (i < 131072) {                            // A: 256 mt x 8 kt tiles
        int lane = i & 63, t = i >> 6;
        int mt = t >> 3, kt = t & 7;
        int m = mt * 16 + (lane & 15);
        int k = kt * 32 + (lane >> 4) * 8;
        const float* xs = x + (size_t)m * 256 + k;
        const float* bd = b_dec + k;
        u32 o[4];
#pragma unroll
        for (int j = 0; j < 4; j++) {
            u16 lo = f2bf(xs[2*j]   - bd[2*j]);
            u16 hi = f2bf(xs[2*j+1] - bd[2*j+1]);
            o[j] = (u32)lo | ((u32)hi << 16);
        }
        *(uint4*)(Ap + (size_t)i * 8) = make_uint4(o[0], o[1], o[2], o[3]);
    } else if (i < 393216) {                     // W_enc: 512 nt x 8 kt tiles
        int j0 = i - 131072;
        int lane = j0 & 63, t = j0 >> 6;
        int nt = t >> 3, kt = t & 7;
        int n = nt * 16 + (lane & 15);
        int k = kt * 32 + (lane >> 4) * 8;
        const float* ws = W_enc + (size_t)n * 256 + k;
        u32 o[4];
#pragma unroll
        for (int j = 0; j < 4; j++) {
            u16 lo = f2bf(ws[2*j]);
            u16 hi = f2bf(ws[2*j+1]);
            o[j] = (u32)lo | ((u32)hi << 16);
        }
        *(uint4*)(Wb + (size_t)j0 * 8) = make_uint4(o[0], o[1], o[2], o[3]);
    } else if (i < 655360) {                     // W_dec: plain bf16, 8/thread
        int j0 = i - 393216;
        const float* ws = W_dec + (size_t)j0 * 8;
        u32 o[4];
#pragma unroll
        for (int j = 0; j < 4; j++) {
            u16 lo = f2bf(ws[2*j]);
            u16 hi = f2bf(ws[2*j+1]);
            o[j] = (u32)lo | ((u32)hi << 16);
        }
        *(uint4*)(Wd + (size_t)j0 * 8) = make_uint4(o[0], o[1], o[2], o[3]);
    } else if (i < 659456) {                     // zero spill counters
        cnt[i - 655360] = 0;
    } else {                                     // zero seg: 16 MB, uint4 each
        int j1 = i - 659456;                     // 0..1048575
        *(uint4*)(seg + (size_t)j1 * 4) = make_uint4(0u, 0u, 0u, 0u);
    }
}

// ---------------------------------------------------------------------------
// Kernel 1 (v6): ZERO-LDS, ZERO-BARRIER encode GEMM at 4 waves/SIMD.
// [R1: barrier drain = 47us. R2: pointer-selected arrays -> scratch = 56us.
//  R3/R4: zero-barrier works (~35us) but NEUTRAL to L2-traffic geometry ->
//  not byte-bound. Occupancy tracks encode time across R0-R4 (4/SIMD=32,
//  2/SIMD=34-56): latency-stall-bound. v6 doubles occupancy 2->4 waves/SIMD.]
// Per-wave state cut to ~100 VGPR: 16 cols/wave -> B strip = 8 short8 =
// 32 VGPR (loaded once); acc 4; NO A double-buffer — LOADA(next chunk)
// issued between MFMA block and EMIT phase, so EMIT VALU (~120cyc) + 4-way
// wave interleave covers L2 latency (~200cyc). launch_bounds(512,4).
// Grid 512 blocks x 8 waves = 4096 waves = exactly 4/SIMD.
// Block = 128 cols x 512 rows; wave = 16 cols x 512 rows as 32 chunks of 16.
// Emit: 16-col cell owned by ONE wave -> ballot-prefix slots (<2) race-free
// direct store to seg[row][cell=n>>4][2]; overflow -> global spill.
// XCD: id%8=c -> 8 col-blocks/XCD: W 512KB + A 2MB fits 4MB L2.
// ---------------------------------------------------------------------------
#define LOADA(dst, mt) do {                                                    \
    _Pragma("unroll")                                                          \
    for (int kt = 0; kt < 8; kt++)                                             \
        dst[kt] = *(const short8*)(A + ((size_t)((mt) * 8 + kt) * 64 + lane) * 8); \
} while (0)

#define EMIT_RQ(rq) do {                                                       \
    float v = ac[rq] + bias;                                                   \
    bool pass = (v >= 1.984375f);                                              \
    unsigned long long mk = __ballot(pass);                                    \
    u32 mg = (u32)(mk >> (g16 * 16)) & 0xFFFFu;                                \
    if (pass) {                                                                \
        int slot = __popc(mg & ((1u << l16) - 1u));                            \
        int fx = (int)(v * 65536.f); if (fx > 0x7FFFF) fx = 0x7FFFF;           \
        u32 e = ((u32)(n0 + l16) << 19) | (u32)fx;                             \
        int grow = rowbase + rq;                                               \
        if (slot < 2) {                                                        \
            seg[(size_t)grow * 1024 + cell2 + slot] = e;                       \
        } else {                                                               \
            u32 gs = atomicAdd(&cnt[grow], 1u);                                \
            if (gs < SCAP) spill[(size_t)grow * SCAP + gs] = e;                \
        }                                                                      \
    }                                                                          \
} while (0)

__global__ __launch_bounds__(512, 4) void encode_gemm(const u16* __restrict__ A,
                                                      const u16* __restrict__ W,
                                                      const float* __restrict__ b_enc,
                                                      u32* __restrict__ cnt,
                                                      u32* __restrict__ seg,
                                                      u32* __restrict__ spill) {
    const int tid  = threadIdx.x;
    const int lane = tid & 63;
    const int wave = tid >> 6;          // 0..7
    const int g16  = lane >> 4;         // 16-lane row group
    const int l16  = lane & 15;

    const int id = blockIdx.x;          // 512 blocks (2 per CU)
    const int c  = id & 7, j = id >> 3; // c = XCD, j = 0..63
    const int bx = c * 8 + (j & 7);     // col-block 0..63 (128 cols)
    const int rg = j >> 3;              // row-group 0..7 (512 rows)

    const int n0    = bx * 128 + wave * 16;    // wave's 16-col strip
    const int nt0   = bx * 8 + wave;           // wave's n-tile (of 512)
    const int cell2 = (n0 >> 4) * 2;           // seg cell base (u32 units)
    const int mtb   = rg * 32;                 // block's first m-tile

    // ---- B strip in registers, loaded once: 8 x short8 = 32 VGPR ----------
    short8 b[8];
#pragma unroll
    for (int kt = 0; kt < 8; kt++)
        b[kt] = *(const short8*)(W + ((size_t)(nt0 * 8 + kt) * 64 + lane) * 8);
    const float bias = b_enc[n0 + l16];

    // ---- stream 32 chunks of 16 rows; single A buffer, load-early ----------
    short8 a[8];
    LOADA(a, mtb);

    for (int it = 0; it < 32; it++) {
        f32x4 ac = {0.f, 0.f, 0.f, 0.f};
#pragma unroll
        for (int kt = 0; kt < 8; kt++)
            ac = __builtin_amdgcn_mfma_f32_16x16x32_bf16(a[kt], b[kt], ac, 0, 0, 0);
        // prefetch next chunk while EMIT VALU runs (covers L2 latency)
        const int mtn = mtb + (it + 1 < 32 ? it + 1 : 31);
        LOADA(a, mtn);
        // C/D layout: col(n)=lane&15, row(m)=(lane>>4)*4+reg  [m89-verified]
        const int rowbase = rg * 512 + it * 16 + g16 * 4;
        EMIT_RQ(0);
        EMIT_RQ(1);
        EMIT_RQ(2);
        EMIT_RQ(3);
    }
}

// ---------------------------------------------------------------------------
// Kernel 2: per row — read 1024 seg slots (ONE coalesced 4 KB burst,
// row-major seg[4096][512][2], byte-identical read path) (+spills) ->
// q-hist brackets T -> certain-in (v > Thi+2B, z = v) / ambiguous band
// (fp64 refine, exact ordering) -> decode with bf16 W_dec. Exact streaming
// fallback if screen invalid (never expected). XCD row-grouping.
// (unchanged from R3/R4)
// ---------------------------------------------------------------------------
__global__ __launch_bounds__(256) void select_decode(const u32* __restrict__ cnt,
                                                     const u32* __restrict__ seg,
                                                     const u32* __restrict__ spill,
                                                     const float* __restrict__ x,
                                                     const float* __restrict__ W_enc,
                                                     const float* __restrict__ b_enc,
                                                     const u16* __restrict__ Wd,
                                                     const float* __restrict__ b_dec,
                                                     float* __restrict__ out) {
    const int r    = (blockIdx.x & 7) * 512 + (blockIdx.x >> 3);   // XCD-grouped
    const int tid  = threadIdx.x;
    const int lane = tid & 63;
    const int wave = tid >> 6;
    const int grp  = tid >> 4;     // 16 groups of 16 lanes
    const int l16  = tid & 15;

    __shared__ float s_sae[256];
    __shared__ u32   hist[256];
    __shared__ int   wtot[4];
    __shared__ int   s_t32;
    __shared__ u32   s_m, s_c1, s_namb, s_nref;
    __shared__ int   cidx[CMAX];
    __shared__ float cval[CMAX];
    __shared__ u8    csat[CMAX];
    __shared__ short ridx[RCAP];
    __shared__ float rex[RCAP];
    __shared__ float sel_val[32];
    __shared__ int   sel_idx[32];

    s_sae[tid] = x[(size_t)r * 256 + tid] - b_dec[tid];
    hist[tid] = 0;
    if (tid == 0) { s_t32 = -1; s_m = 0; s_c1 = 0; s_namb = 0; s_nref = 0; }
    if (tid < 32) { sel_val[tid] = 0.f; sel_idx[tid] = 0; }
    __syncthreads();

    auto add_cand = [&](u32 e) {
        int fx = (int)(e & 0x7FFFFu);
        float v = (float)fx * 1.52587890625e-5f;   // /65536
        u32 p = atomicAdd(&s_m, 1u);
        if (p < CMAX) {
            cidx[p] = (int)(e >> 19);
            cval[p] = v;
            csat[p] = (fx == 0x7FFFF);
        }
        int q = (int)(v * 32.f + 0.5f); if (q > 255) q = 255;
        atomicAdd(&hist[q], 1u);
    };
    auto find_t32 = [&]() {
        int c = (int)hist[tid];
        int s = c;
#pragma unroll
        for (int off = 1; off < 64; off <<= 1) {
            int v = __shfl_down(s, off);
            if (lane + off < 64) s += v;
        }
        if (lane == 0) wtot[wave] = s;
        __syncthreads();
        int hisum = 0;
        for (int ww = wave + 1; ww < 4; ww++) hisum += wtot[ww];
        int S = s + hisum;
        if (S >= 32 && (S - c) < 32) s_t32 = tid;   // unique transition bin
        __syncthreads();
    };
    auto exact_col = [&](int col) -> double {
        const float4* wr = (const float4*)(W_enc + (size_t)col * 256 + l16 * 16);
        double s = 0.0;
#pragma unroll
        for (int u = 0; u < 4; u++) {
            float4 wv = wr[u];
            const float* sp = &s_sae[l16 * 16 + u * 4];
            s += (double)wv.x * (double)sp[0] + (double)wv.y * (double)sp[1]
               + (double)wv.z * (double)sp[2] + (double)wv.w * (double)sp[3];
        }
#pragma unroll
        for (int off = 8; off; off >>= 1) s += __shfl_down(s, off, 16);
        return s;
    };

    // --- gather candidates: one coalesced 4 KB burst (1024 slots/row) -------
    {
        uint4 ee = *(const uint4*)(seg + (size_t)r * 1024 + tid * 4);
        if (ee.x) add_cand(ee.x);
        if (ee.y) add_cand(ee.y);
        if (ee.z) add_cand(ee.z);
        if (ee.w) add_cand(ee.w);
    }
    const int nsp_all = (int)cnt[r];
    const int nsp = nsp_all < SCAP ? nsp_all : SCAP;
    for (int i = tid; i < nsp; i += 256)
        add_cand(spill[(size_t)r * SCAP + i]);
    __syncthreads();
    const int m = (int)s_m < CMAX ? (int)s_m : CMAX;
    find_t32();

    // t32 >= 67 <=> Tlo-2B >= 1.984 (emit screen) -> non-listed certainly out
    const bool fb_pre = (nsp_all > SCAP) || ((int)s_m > CMAX) || (s_t32 < 67);

    if (!fb_pre) {
        const float Thi = (s_t32 + 0.5f) * 0.03125f;
        const float Tlo = (s_t32 - 0.5f) * 0.03125f;
        for (int i = tid; i < m; i += 256) {
            float v = cval[i];
            if (!csat[i] && v > Thi + 2.f * BERR) {   // certainly in true top-32
                u32 p = atomicAdd(&s_c1, 1u);
                if (p < 32) { sel_val[p] = v; sel_idx[p] = cidx[i]; }
            } else if (csat[i] || v >= Tlo - 2.f * BERR) {  // ambiguous band
                u32 p = atomicAdd(&s_namb, 1u);
                if (p < RCAP) ridx[p] = (short)i;
            }
        }
    }
    __syncthreads();
    const int c1 = (int)s_c1, namb = (int)s_namb;
    const bool fb = fb_pre || (namb > RCAP) || (c1 > 31);

    if (!fb) {
        // --- fp64 refine of ambiguous band: 2 per 16-lane group per pass ----
        for (int t0 = 0; t0 < namb; t0 += 32) {
            int cA = t0 + grp, cB = t0 + grp + 16;
            if (cA < namb) {
                int iA = cidx[ridx[cA]];
                double s = exact_col(iA);
                if (l16 == 0) {
                    float f = (float)(s + (double)b_enc[iA]);
                    rex[cA] = f > 0.f ? f : 0.f;
                }
            }
            if (cB < namb) {
                int iB = cidx[ridx[cB]];
                double s = exact_col(iB);
                if (l16 == 0) {
                    float f = (float)(s + (double)b_enc[iB]);
                    rex[cB] = f > 0.f ? f : 0.f;
                }
            }
        }
        __syncthreads();

        // --- top (32-c1) of band by (exact desc, idx asc) --------------------
        const int need = 32 - c1;
        for (int k = tid; k < namb; k += 256) {
            float vi = rex[k];
            int   ii = cidx[ridx[k]];
            int rank = 0;
            for (int j = 0; j < namb; j++) {
                float vj = rex[j];
                rank += (vj > vi) || (vj == vi && cidx[ridx[j]] < ii);
            }
            if (rank < need) { sel_val[c1 + rank] = vi; sel_idx[c1 + rank] = ii; }
        }
        __syncthreads();
    } else {
        // --- exact streaming fallback over all 8192 cols (never expected) ---
        hist[tid] = 0;
        if (tid == 0) { s_t32 = -1; s_nref = 0; }
        __syncthreads();
        for (int it = 0; it < 512; it++) {
            int col = it * 16 + grp;
            double s = exact_col(col);
            if (l16 == 0) {
                float f = (float)(s + (double)b_enc[col]);
                f = f > 0.f ? f : 0.f;
                int q = (int)(f * 32.f + 0.5f); if (q > 255) q = 255;
                if (q >= 1) atomicAdd(&hist[q], 1u);
            }
        }
        __syncthreads();
        find_t32();
        int qlo = s_t32 >= 3 ? s_t32 - 2 : 1;
        for (int pass = 0; pass < 2; pass++) {
            for (int it = 0; it < 512; it++) {
                int col = it * 16 + grp;
                double s = exact_col(col);
                if (l16 == 0) {
                    float f = (float)(s + (double)b_enc[col]);
                    f = f > 0.f ? f : 0.f;
                    int q = (int)(f * 32.f + 0.5f); if (q > 255) q = 255;
                    if (q >= qlo) {
                        u32 p = atomicAdd(&s_nref, 1u);
                        if (p < CMAX) { cidx[p] = col; cval[p] = f; }
                    }
                }
            }
            __syncthreads();
            if ((int)s_nref <= CMAX) break;
            if (tid == 0) s_nref = 0;
            qlo = s_t32 > 0 ? s_t32 : 1;
            __syncthreads();
        }
        int nf = (int)s_nref; if (nf > CMAX) nf = CMAX;
        for (int k = tid; k < nf; k += 256) {
            float vi = cval[k]; int ii = cidx[k]; int rank = 0;
            for (int j = 0; j < nf; j++)
                rank += (cval[j] > vi) || (cval[j] == vi && cidx[j] < ii);
            if (rank < 32) { sel_val[rank] = vi; sel_idx[rank] = ii; }
        }
        __syncthreads();
    }

    // --- decode: out[r] = b_dec + sum_k z_k * bf16(W_dec)[idx_k] ------------
    u16 wv[32];
#pragma unroll
    for (int k = 0; k < 32; k++)
        wv[k] = Wd[(size_t)sel_idx[k] * 256 + tid];   // 32 independent loads
    float acc = b_dec[tid];
#pragma unroll
    for (int k = 0; k < 32; k++)
        acc += sel_val[k] * bf2f(wv[k]);
    out[(size_t)r * 256 + tid] = acc;
}

// ---------------------------------------------------------------------------
// ws layout (~27.5 MB; ws_size is 256 MB):
//   cnt 16 KB | seg 16 MB (seg[4096][512][2] u32, pre-zeroed by prep) |
//   spill 1.5 MB | Ap 2 MB | Wb 4 MB | Wd 4 MB
// ---------------------------------------------------------------------------
extern "C" void kernel_launch(void* const* d_in, const int* in_sizes, int n_in,
                              void* d_out, int out_size, void* d_ws, size_t ws_size,
                              hipStream_t stream) {
    const float* x     = (const float*)d_in[0];   // [4096,256] f32
    const float* W_enc = (const float*)d_in[1];   // [8192,256] f32
    const float* b_enc = (const float*)d_in[2];   // [8192]     f32
    const float* W_dec = (const float*)d_in[3];   // [8192,256] f32
    const float* b_dec = (const float*)d_in[4];   // [256]      f32
    float* out = (float*)d_out;                   // [4096,256] f32

    u32* cnt   = (u32*)d_ws;                            // 16 KB spill counters
    u32* seg   = cnt + 4096;                            // 16 MB candidate slots
    u32* spill = seg + (size_t)4096 * 1024;             // 1.5 MB spill lists
    u16* Ap    = (u16*)(spill + (size_t)4096 * SCAP);   // 2 MB swizzled bf16(x-b_dec)
    u16* Wb    = Ap + (size_t)4096 * 256;               // 4 MB swizzled bf16(W_enc)
    u16* Wd    = Wb + (size_t)8192 * 256;               // 4 MB bf16(W_dec)

    prep_convert<<<6672, 256, 0, stream>>>(x, b_dec, W_enc, W_dec, Ap, Wb, Wd, cnt, seg);
    encode_gemm<<<512, 512, 0, stream>>>(Ap, Wb, b_enc, cnt, seg, spill);
    select_decode<<<4096, 256, 0, stream>>>(cnt, seg, spill, x, W_enc, b_enc, Wd, b_dec, out);
}